// Round 1
// baseline (319.245 us; speedup 1.0000x reference)
//
#include <hip/hip_runtime.h>
#include <stdint.h>

#define DEVI __device__ __forceinline__

typedef float f32x4 __attribute__((ext_vector_type(4)));
typedef float float4v __attribute__((ext_vector_type(4)));
typedef short short8 __attribute__((ext_vector_type(8)));
typedef uint16_t u16x4 __attribute__((ext_vector_type(4)));

// fold softmax scale (1/sqrt(64)) and log2(e) into Q so softmax uses exp2
static constexpr float QSCALE = 0.125f * 1.44269504088896340736f;

DEVI uint16_t f2bf(float f) {
  uint32_t u = __builtin_bit_cast(uint32_t, f);
  return (uint16_t)((u + 0x7FFFu + ((u >> 16) & 1u)) >> 16);  // RNE
}

DEVI void gload_lds16(const void* g, void* lds) {
  __builtin_amdgcn_global_load_lds(
      reinterpret_cast<const uint32_t __attribute__((address_space(1)))*>(
          reinterpret_cast<uintptr_t>(g)),
      reinterpret_cast<uint32_t __attribute__((address_space(3)))*>(
          reinterpret_cast<uintptr_t>(lds)),
      16, 0, 0);
}

// swizzled read of a bf16x8 fragment from a [rows][64] bf16 LDS tile (128B rows)
// swizzle: byte ^= (row&7)<<4  (matches pre-swizzled global_load_lds source)
DEVI short8 lds_frag(const uint16_t* tile, int row, int kByte) {
  return *(const short8*)((const char*)tile + row * 128 + (kByte ^ ((row & 7) << 4)));
}

DEVI f32x4 mfma16(short8 a, short8 b, f32x4 c) {
  return __builtin_amdgcn_mfma_f32_16x16x32_bf16(a, b, c, 0, 0, 0);
}

// ---------------- prep kernels ----------------

__global__ void k_cvt_x(const float* __restrict__ x, uint16_t* __restrict__ xb) {
  const int i = blockIdx.x * blockDim.x + threadIdx.x;  // 8-elem chunks
  const float4v* p = (const float4v*)x + (size_t)i * 2;
  float4v a = p[0], b = p[1];
  alignas(16) uint16_t r[8];
  r[0] = f2bf(a[0]); r[1] = f2bf(a[1]); r[2] = f2bf(a[2]); r[3] = f2bf(a[3]);
  r[4] = f2bf(b[0]); r[5] = f2bf(b[1]); r[6] = f2bf(b[2]); r[7] = f2bf(b[3]);
  *((short8*)xb + i) = *(const short8*)r;
}

__global__ void k_cvt_wo(const float* __restrict__ Wo, uint16_t* __restrict__ Wob) {
  const int i = blockIdx.x * blockDim.x + threadIdx.x;
  const float4v* p = (const float4v*)Wo + (size_t)i * 2;
  float4v a = p[0], b = p[1];
  alignas(16) uint16_t r[8];
  r[0] = f2bf(a[0]); r[1] = f2bf(a[1]); r[2] = f2bf(a[2]); r[3] = f2bf(a[3]);
  r[4] = f2bf(b[0]); r[5] = f2bf(b[1]); r[6] = f2bf(b[2]); r[7] = f2bf(b[3]);
  *((short8*)Wob + i) = *(const short8*)r;
}

// Build Wqkv_t [N=3072][K=1024] bf16 where row n = (sect,h,dd):
//   Wt[n][k] = Wsect[h][k][dd]   (transpose via LDS tile, coalesced both sides)
// grid: sect(3) x h(16) x kc(16) = 768 blocks, 256 threads
__global__ void k_cvt_wqkv(const float* __restrict__ Wq, const float* __restrict__ Wk,
                           const float* __restrict__ Wv, uint16_t* __restrict__ Wt) {
  __shared__ float tile[64][65];
  const int bx = blockIdx.x;
  const int sect = bx >> 8, h = (bx >> 4) & 15, kc = bx & 15;
  const float* W = sect == 0 ? Wq : (sect == 1 ? Wk : Wv);
  const float scal = sect == 0 ? QSCALE : 1.0f;
  const int t = threadIdx.x;
  // load [64 k][64 dd] fp32 tile (coalesced)
  const int r = t >> 2, cbase = (t & 3) * 16;
  const float* src = W + ((size_t)(h * 1024 + kc * 64 + r)) * 64 + cbase;
#pragma unroll
  for (int j = 0; j < 4; ++j) {
    float4v v = *(const float4v*)(src + j * 4);
    tile[r][cbase + j * 4 + 0] = v[0];
    tile[r][cbase + j * 4 + 1] = v[1];
    tile[r][cbase + j * 4 + 2] = v[2];
    tile[r][cbase + j * 4 + 3] = v[3];
  }
  __syncthreads();
  // write transposed bf16 (coalesced)
  const int dd = t >> 2, kp = (t & 3) * 16;
  alignas(16) uint16_t tmp[16];
#pragma unroll
  for (int j = 0; j < 16; ++j) tmp[j] = f2bf(tile[kp + j][dd] * scal);
  const int n = sect * 1024 + h * 64 + dd;
  uint16_t* dst = Wt + (size_t)n * 1024 + kc * 64 + kp;
  *(short8*)dst = *(const short8*)tmp;
  *((short8*)dst + 1) = *(const short8*)(tmp + 8);
}

// ---------------- GEMM (K=1024, 128x128 tile, BK=64, dbuf LDS) ----------------
// MODE 0: QKV projection epilogue (scatter Q/K/V^T bf16 + bias)
// MODE 1: final projection epilogue (fp32 out + bo)
template <int MODE>
__global__ __launch_bounds__(256, 2) void gemm_k1024(
    const uint16_t* __restrict__ A, const uint16_t* __restrict__ Bt, int tiles_n,
    const float* __restrict__ bias_q, const float* __restrict__ bias_k,
    const float* __restrict__ bias_v,
    uint16_t* __restrict__ Qws, uint16_t* __restrict__ Kws, uint16_t* __restrict__ Vtws,
    float* __restrict__ outf) {
  __shared__ uint16_t As[2][128 * 64];
  __shared__ uint16_t Bs[2][128 * 64];

  const int tid = threadIdx.x, lane = tid & 63, wv = tid >> 6;
  const int m0 = (blockIdx.x / tiles_n) * 128;
  const int n0 = (blockIdx.x % tiles_n) * 128;
  const int wm = (wv >> 1) * 64, wn = (wv & 1) * 64;
  const int rin = lane >> 3;
  const int csw = ((lane & 7) ^ rin) * 16;  // pre-swizzled source chunk (rule #21)

  const char* gA = (const char*)A;
  const char* gB = (const char*)Bt;

  f32x4 acc[4][4];
#pragma unroll
  for (int mi = 0; mi < 4; ++mi)
#pragma unroll
    for (int ni = 0; ni < 4; ++ni) acc[mi][ni] = (f32x4){0.f, 0.f, 0.f, 0.f};

  auto stage = [&](int buf, int kt) {
    const int k0b = kt * 128;  // byte offset of k within 2048B row
#pragma unroll
    for (int i = 0; i < 4; ++i) {
      const int rb = wv * 32 + i * 8;
      gload_lds16(gA + (size_t)(m0 + rb + rin) * 2048 + k0b + csw, &As[buf][rb * 64]);
      gload_lds16(gB + (size_t)(n0 + rb + rin) * 2048 + k0b + csw, &Bs[buf][rb * 64]);
    }
  };

  stage(0, 0);
  const int kb0 = (lane >> 4) * 16;
  for (int kt = 0; kt < 16; ++kt) {
    const int buf = kt & 1;
    __syncthreads();  // staging of buf complete (compiler drains vmcnt)
    if (kt + 1 < 16) stage(buf ^ 1, kt + 1);
#pragma unroll
    for (int kk = 0; kk < 2; ++kk) {
      short8 af[4], bfr[4];
#pragma unroll
      for (int i = 0; i < 4; ++i) {
        af[i] = lds_frag(As[buf], wm + i * 16 + (lane & 15), kk * 64 + kb0);
        bfr[i] = lds_frag(Bs[buf], wn + i * 16 + (lane & 15), kk * 64 + kb0);
      }
#pragma unroll
      for (int mi = 0; mi < 4; ++mi)
#pragma unroll
        for (int ni = 0; ni < 4; ++ni) acc[mi][ni] = mfma16(af[mi], bfr[ni], acc[mi][ni]);
    }
    __syncthreads();  // all reads of buf done before it is re-staged
  }

  // ---- epilogue ----
  const int col0 = n0 + wn + (lane & 15);
  const int row0 = m0 + wm + ((lane >> 4) << 2);
  if (MODE == 1) {
#pragma unroll
    for (int ni = 0; ni < 4; ++ni) {
      const int n = col0 + ni * 16;
      const float bv = bias_q[n];  // bo
#pragma unroll
      for (int mi = 0; mi < 4; ++mi) {
        const int mrow = row0 + mi * 16;
#pragma unroll
        for (int r = 0; r < 4; ++r)
          outf[(size_t)(mrow + r) * 1024 + n] = acc[mi][ni][r] + bv;
      }
    }
  } else {
#pragma unroll
    for (int ni = 0; ni < 4; ++ni) {
      const int n = col0 + ni * 16;
      const int sect = n >> 10, h = (n >> 6) & 15, dd = n & 63;
      float bv;
      if (sect == 0) bv = bias_q[h * 64 + dd] * QSCALE;
      else if (sect == 1) bv = bias_k[h * 64 + dd];
      else bv = bias_v[h * 64 + dd];
#pragma unroll
      for (int mi = 0; mi < 4; ++mi) {
        const int mrow = row0 + mi * 16;
        const int b = mrow >> 11, s = mrow & 2047;
        const int bh = b * 16 + h;
        if (sect == 2) {
          u16x4 pk;
#pragma unroll
          for (int r = 0; r < 4; ++r) pk[r] = f2bf(acc[mi][ni][r] + bv);
          *(u16x4*)(Vtws + ((size_t)bh * 64 + dd) * 2048 + s) = pk;  // V^T [bh][d][s]
        } else {
          uint16_t* dst = (sect == 0 ? Qws : Kws) + ((size_t)bh * 2048 + s) * 64 + dd;
#pragma unroll
          for (int r = 0; r < 4; ++r) dst[(size_t)r * 64] = f2bf(acc[mi][ni][r] + bv);
        }
      }
    }
  }
}

// ---------------- flash attention ----------------
// grid: bh(64) x qtile(16); block 256 = 4 waves, each wave owns 32 q-rows.
__global__ __launch_bounds__(256, 2) void attn_fa(
    const uint16_t* __restrict__ Qws, const uint16_t* __restrict__ Kws,
    const uint16_t* __restrict__ Vtws, uint16_t* __restrict__ AttO) {
  __shared__ uint16_t Kl[64 * 64];
  __shared__ uint16_t Vl[64 * 64];
  __shared__ uint16_t Pl[4][32 * 64];

  const int tid = threadIdx.x, lane = tid & 63, wv = tid >> 6;
  const int bh = blockIdx.x >> 4;
  const int q0 = (blockIdx.x & 15) * 128;
  const int rin = lane >> 3;
  const int csw = ((lane & 7) ^ rin) * 16;
  const int kb0 = (lane >> 4) * 16;

  const uint16_t* Qb = Qws + (size_t)bh * (2048 * 64);
  const uint16_t* Kb = Kws + (size_t)bh * (2048 * 64);
  const uint16_t* Vb = Vtws + (size_t)bh * (64 * 2048);

  // Q fragments held in registers for the whole block
  short8 qf[2][2];
#pragma unroll
  for (int mi = 0; mi < 2; ++mi)
#pragma unroll
    for (int kk = 0; kk < 2; ++kk)
      qf[mi][kk] = *(const short8*)(Qb + (size_t)(q0 + wv * 32 + mi * 16 + (lane & 15)) * 64 +
                                    kk * 32 + ((lane >> 4) << 3));

  f32x4 o[2][4];
  float mr[2][4], lr[2][4];
#pragma unroll
  for (int mi = 0; mi < 2; ++mi) {
#pragma unroll
    for (int ni = 0; ni < 4; ++ni) o[mi][ni] = (f32x4){0.f, 0.f, 0.f, 0.f};
#pragma unroll
    for (int r = 0; r < 4; ++r) { mr[mi][r] = -1e30f; lr[mi][r] = 0.f; }
  }

  for (int kt = 0; kt < 32; ++kt) {
    // stage K tile [64 keys][64 d] and V^T tile [64 d][64 keys] (swizzled source)
    {
      const int k0 = kt * 64;
#pragma unroll
      for (int i = 0; i < 2; ++i) {
        const int rb = wv * 16 + i * 8;
        gload_lds16((const char*)Kb + (size_t)(k0 + rb + rin) * 128 + csw, &Kl[rb * 64]);
        gload_lds16((const char*)Vb + ((size_t)(rb + rin) * 2048 + k0) * 2 + csw, &Vl[rb * 64]);
      }
    }
    __syncthreads();  // staging complete

    // S = Q K^T (in log2 units; scale folded into Q)
    f32x4 sc[2][4];
#pragma unroll
    for (int mi = 0; mi < 2; ++mi)
#pragma unroll
      for (int ni = 0; ni < 4; ++ni) sc[mi][ni] = (f32x4){0.f, 0.f, 0.f, 0.f};
#pragma unroll
    for (int kk = 0; kk < 2; ++kk) {
      short8 kf[4];
#pragma unroll
      for (int ni = 0; ni < 4; ++ni)
        kf[ni] = lds_frag(Kl, ni * 16 + (lane & 15), kk * 64 + kb0);
#pragma unroll
      for (int mi = 0; mi < 2; ++mi)
#pragma unroll
        for (int ni = 0; ni < 4; ++ni) sc[mi][ni] = mfma16(qf[mi][kk], kf[ni], sc[mi][ni]);
    }

    // online softmax (wave-parallel: 16-lane shfl_xor reduction per row)
#pragma unroll
    for (int mi = 0; mi < 2; ++mi) {
      f32x4 mx = sc[mi][0];
#pragma unroll
      for (int ni = 1; ni < 4; ++ni)
#pragma unroll
        for (int r = 0; r < 4; ++r) mx[r] = fmaxf(mx[r], sc[mi][ni][r]);
#pragma unroll
      for (int d = 1; d < 16; d <<= 1)
#pragma unroll
        for (int r = 0; r < 4; ++r) mx[r] = fmaxf(mx[r], __shfl_xor(mx[r], d, 64));
      float al[4];
#pragma unroll
      for (int r = 0; r < 4; ++r) {
        const float mn = fmaxf(mr[mi][r], mx[r]);
        al[r] = __builtin_amdgcn_exp2f(mr[mi][r] - mn);
        mr[mi][r] = mn;
      }
      f32x4 ps = (f32x4){0.f, 0.f, 0.f, 0.f};
#pragma unroll
      for (int ni = 0; ni < 4; ++ni)
#pragma unroll
        for (int r = 0; r < 4; ++r) {
          const float p = __builtin_amdgcn_exp2f(sc[mi][ni][r] - mr[mi][r]);
          sc[mi][ni][r] = p;
          ps[r] += p;
        }
#pragma unroll
      for (int d = 1; d < 16; d <<= 1)
#pragma unroll
        for (int r = 0; r < 4; ++r) ps[r] += __shfl_xor(ps[r], d, 64);
#pragma unroll
      for (int r = 0; r < 4; ++r) lr[mi][r] = lr[mi][r] * al[r] + ps[r];
#pragma unroll
      for (int ni = 0; ni < 4; ++ni)
#pragma unroll
        for (int r = 0; r < 4; ++r) o[mi][ni][r] *= al[r];
      // write P tile to this wave's LDS region (bf16, swizzled)
      char* pb = (char*)&Pl[wv][0];
#pragma unroll
      for (int ni = 0; ni < 4; ++ni) {
        const int c2 = (ni * 16 + (lane & 15)) * 2;
#pragma unroll
        for (int r = 0; r < 4; ++r) {
          const int row = mi * 16 + ((lane >> 4) << 2) + r;
          *(uint16_t*)(pb + row * 128 + (c2 ^ ((row & 7) << 4))) = f2bf(sc[mi][ni][r]);
        }
      }
    }

    // O += P @ V   (B-operand from V^T tile: contiguous swizzled reads)
#pragma unroll
    for (int kk = 0; kk < 2; ++kk) {
      short8 pf[2], vf[4];
#pragma unroll
      for (int mi = 0; mi < 2; ++mi)
        pf[mi] = lds_frag(Pl[wv], mi * 16 + (lane & 15), kk * 64 + kb0);
#pragma unroll
      for (int ni = 0; ni < 4; ++ni)
        vf[ni] = lds_frag(Vl, ni * 16 + (lane & 15), kk * 64 + kb0);
#pragma unroll
      for (int mi = 0; mi < 2; ++mi)
#pragma unroll
        for (int ni = 0; ni < 4; ++ni) o[mi][ni] = mfma16(pf[mi], vf[ni], o[mi][ni]);
    }
    __syncthreads();  // all waves done with Kl/Vl before next stage
  }

  // epilogue: normalize and store concat-head layout [b][s][h*64+dd]
  const int b = bh >> 4, h = bh & 15;
#pragma unroll
  for (int mi = 0; mi < 2; ++mi)
#pragma unroll
    for (int r = 0; r < 4; ++r) {
      const int s = q0 + wv * 32 + mi * 16 + ((lane >> 4) << 2) + r;
      const float inv = 1.0f / lr[mi][r];
#pragma unroll
      for (int ni = 0; ni < 4; ++ni) {
        const int col = h * 64 + ni * 16 + (lane & 15);
        AttO[((size_t)b * 2048 + s) * 1024 + col] = f2bf(o[mi][ni][r] * inv);
      }
    }
}

// ---------------- launcher ----------------

extern "C" void kernel_launch(void* const* d_in, const int* in_sizes, int n_in,
                              void* d_out, int out_size, void* d_ws, size_t ws_size,
                              hipStream_t stream) {
  (void)in_sizes; (void)n_in; (void)out_size; (void)ws_size;
  const float* x  = (const float*)d_in[0];
  const float* Wq = (const float*)d_in[1];
  const float* bq = (const float*)d_in[2];
  const float* Wk = (const float*)d_in[3];
  const float* bk = (const float*)d_in[4];
  const float* Wv = (const float*)d_in[5];
  const float* bv = (const float*)d_in[6];
  const float* Wo = (const float*)d_in[7];
  const float* bo = (const float*)d_in[8];
  float* out = (float*)d_out;

  char* ws = (char*)d_ws;
  // layout (75.5 MB total); AttO aliases Xb (Xb dead after GEMM1)
  uint16_t* Xb   = (uint16_t*)(ws);                 // [8192][1024] bf16
  uint16_t* AttO = (uint16_t*)(ws);                 // [8192][1024] bf16 (alias)
  uint16_t* Wqkv = (uint16_t*)(ws + 16777216);      // [3072][1024] bf16
  uint16_t* Wob  = (uint16_t*)(ws + 23068672);      // [1024][1024] bf16
  uint16_t* Qws  = (uint16_t*)(ws + 25165824);      // [64][2048][64] bf16
  uint16_t* Kws  = (uint16_t*)(ws + 41943040);      // [64][2048][64] bf16
  uint16_t* Vt   = (uint16_t*)(ws + 58720256);      // [64][64][2048] bf16

  k_cvt_x<<<4096, 256, 0, stream>>>(x, Xb);
  k_cvt_wqkv<<<768, 256, 0, stream>>>(Wq, Wk, Wv, Wqkv);
  k_cvt_wo<<<512, 256, 0, stream>>>(Wo, Wob);
  gemm_k1024<0><<<64 * 24, 256, 0, stream>>>(Xb, Wqkv, 24, bq, bk, bv, Qws, Kws, Vt, nullptr);
  attn_fa<<<1024, 256, 0, stream>>>(Qws, Kws, Vt, AttO);
  gemm_k1024<1><<<64 * 8, 256, 0, stream>>>(AttO, Wob, 8, bo, nullptr, nullptr,
                                            nullptr, nullptr, nullptr, out);
}

// Round 2
// 203.550 us; speedup vs baseline: 1.5684x; 1.5684x over previous
//
#include <hip/hip_runtime.h>
#include <stdint.h>

#define DEVI __device__ __forceinline__

typedef float f32x4 __attribute__((ext_vector_type(4)));
typedef float f32x16 __attribute__((ext_vector_type(16)));
typedef float float4v __attribute__((ext_vector_type(4)));
typedef short short8 __attribute__((ext_vector_type(8)));
typedef uint16_t u16x4 __attribute__((ext_vector_type(4)));
typedef uint32_t u32x4 __attribute__((ext_vector_type(4)));
typedef int i32x2 __attribute__((ext_vector_type(2)));

// fold softmax scale (1/sqrt(64)) and log2(e) into Q so softmax uses exp2
static constexpr float QSCALE = 0.125f * 1.44269504088896340736f;

DEVI uint16_t f2bf(float f) {
  uint32_t u = __builtin_bit_cast(uint32_t, f);
  return (uint16_t)((u + 0x7FFFu + ((u >> 16) & 1u)) >> 16);  // RNE
}

DEVI void gload_lds16(const void* g, void* lds) {
  __builtin_amdgcn_global_load_lds(
      reinterpret_cast<const uint32_t __attribute__((address_space(1)))*>(
          reinterpret_cast<uintptr_t>(g)),
      reinterpret_cast<uint32_t __attribute__((address_space(3)))*>(
          reinterpret_cast<uintptr_t>(lds)),
      16, 0, 0);
}

// swizzled read of a bf16x8 fragment from a [rows][64] bf16 LDS tile (128B rows)
// swizzle: byte ^= (row&7)<<4  (matches pre-swizzled global_load_lds source)
DEVI short8 lds_frag(const uint16_t* tile, int row, int kByte) {
  return *(const short8*)((const char*)tile + row * 128 + (kByte ^ ((row & 7) << 4)));
}

DEVI f32x4 mfma16(short8 a, short8 b, f32x4 c) {
  return __builtin_amdgcn_mfma_f32_16x16x32_bf16(a, b, c, 0, 0, 0);
}
DEVI f32x16 mfma32(short8 a, short8 b, f32x16 c) {
  return __builtin_amdgcn_mfma_f32_32x32x16_bf16(a, b, c, 0, 0, 0);
}

DEVI uint32_t cvtpk(float lo, float hi) {
  uint32_t r;
  asm("v_cvt_pk_bf16_f32 %0, %1, %2" : "=v"(r) : "v"(lo), "v"(hi));
  return r;
}

// ---------------- prep kernels ----------------

__global__ void k_cvt_x(const float* __restrict__ x, uint16_t* __restrict__ xb) {
  const int i = blockIdx.x * blockDim.x + threadIdx.x;  // 8-elem chunks
  const float4v* p = (const float4v*)x + (size_t)i * 2;
  float4v a = p[0], b = p[1];
  alignas(16) uint16_t r[8];
  r[0] = f2bf(a[0]); r[1] = f2bf(a[1]); r[2] = f2bf(a[2]); r[3] = f2bf(a[3]);
  r[4] = f2bf(b[0]); r[5] = f2bf(b[1]); r[6] = f2bf(b[2]); r[7] = f2bf(b[3]);
  *((short8*)xb + i) = *(const short8*)r;
}

__global__ void k_cvt_wo(const float* __restrict__ Wo, uint16_t* __restrict__ Wob) {
  const int i = blockIdx.x * blockDim.x + threadIdx.x;
  const float4v* p = (const float4v*)Wo + (size_t)i * 2;
  float4v a = p[0], b = p[1];
  alignas(16) uint16_t r[8];
  r[0] = f2bf(a[0]); r[1] = f2bf(a[1]); r[2] = f2bf(a[2]); r[3] = f2bf(a[3]);
  r[4] = f2bf(b[0]); r[5] = f2bf(b[1]); r[6] = f2bf(b[2]); r[7] = f2bf(b[3]);
  *((short8*)Wob + i) = *(const short8*)r;
}

// Build Wqkv_t [N=3072][K=1024] bf16 where row n = (sect,h,dd):
//   Wt[n][k] = Wsect[h][k][dd]   (transpose via LDS tile, coalesced both sides)
__global__ void k_cvt_wqkv(const float* __restrict__ Wq, const float* __restrict__ Wk,
                           const float* __restrict__ Wv, uint16_t* __restrict__ Wt) {
  __shared__ float tile[64][65];
  const int bx = blockIdx.x;
  const int sect = bx >> 8, h = (bx >> 4) & 15, kc = bx & 15;
  const float* W = sect == 0 ? Wq : (sect == 1 ? Wk : Wv);
  const float scal = sect == 0 ? QSCALE : 1.0f;
  const int t = threadIdx.x;
  const int r = t >> 2, cbase = (t & 3) * 16;
  const float* src = W + ((size_t)(h * 1024 + kc * 64 + r)) * 64 + cbase;
#pragma unroll
  for (int j = 0; j < 4; ++j) {
    float4v v = *(const float4v*)(src + j * 4);
    tile[r][cbase + j * 4 + 0] = v[0];
    tile[r][cbase + j * 4 + 1] = v[1];
    tile[r][cbase + j * 4 + 2] = v[2];
    tile[r][cbase + j * 4 + 3] = v[3];
  }
  __syncthreads();
  const int dd = t >> 2, kp = (t & 3) * 16;
  alignas(16) uint16_t tmp[16];
#pragma unroll
  for (int j = 0; j < 16; ++j) tmp[j] = f2bf(tile[kp + j][dd] * scal);
  const int n = sect * 1024 + h * 64 + dd;
  uint16_t* dst = Wt + (size_t)n * 1024 + kc * 64 + kp;
  *(short8*)dst = *(const short8*)tmp;
  *((short8*)dst + 1) = *(const short8*)(tmp + 8);
}

// ---------------- GEMM (K=1024, 128x128 tile, BK=64, dbuf LDS) ----------------
template <int MODE>
__global__ __launch_bounds__(256, 2) void gemm_k1024(
    const uint16_t* __restrict__ A, const uint16_t* __restrict__ Bt, int tiles_n,
    const float* __restrict__ bias_q, const float* __restrict__ bias_k,
    const float* __restrict__ bias_v,
    uint16_t* __restrict__ Qws, uint16_t* __restrict__ Kws, uint16_t* __restrict__ Vtws,
    float* __restrict__ outf) {
  __shared__ uint16_t As[2][128 * 64];
  __shared__ uint16_t Bs[2][128 * 64];

  const int tid = threadIdx.x, lane = tid & 63, wv = tid >> 6;
  const int m0 = (blockIdx.x / tiles_n) * 128;
  const int n0 = (blockIdx.x % tiles_n) * 128;
  const int wm = (wv >> 1) * 64, wn = (wv & 1) * 64;
  const int rin = lane >> 3;
  const int csw = ((lane & 7) ^ rin) * 16;

  const char* gA = (const char*)A;
  const char* gB = (const char*)Bt;

  f32x4 acc[4][4];
#pragma unroll
  for (int mi = 0; mi < 4; ++mi)
#pragma unroll
    for (int ni = 0; ni < 4; ++ni) acc[mi][ni] = (f32x4){0.f, 0.f, 0.f, 0.f};

  auto stage = [&](int buf, int kt) {
    const int k0b = kt * 128;
#pragma unroll
    for (int i = 0; i < 4; ++i) {
      const int rb = wv * 32 + i * 8;
      gload_lds16(gA + (size_t)(m0 + rb + rin) * 2048 + k0b + csw, &As[buf][rb * 64]);
      gload_lds16(gB + (size_t)(n0 + rb + rin) * 2048 + k0b + csw, &Bs[buf][rb * 64]);
    }
  };

  stage(0, 0);
  const int kb0 = (lane >> 4) * 16;
  for (int kt = 0; kt < 16; ++kt) {
    const int buf = kt & 1;
    __syncthreads();
    if (kt + 1 < 16) stage(buf ^ 1, kt + 1);
#pragma unroll
    for (int kk = 0; kk < 2; ++kk) {
      short8 af[4], bfr[4];
#pragma unroll
      for (int i = 0; i < 4; ++i) {
        af[i] = lds_frag(As[buf], wm + i * 16 + (lane & 15), kk * 64 + kb0);
        bfr[i] = lds_frag(Bs[buf], wn + i * 16 + (lane & 15), kk * 64 + kb0);
      }
#pragma unroll
      for (int mi = 0; mi < 4; ++mi)
#pragma unroll
        for (int ni = 0; ni < 4; ++ni) acc[mi][ni] = mfma16(af[mi], bfr[ni], acc[mi][ni]);
    }
    __syncthreads();
  }

  const int col0 = n0 + wn + (lane & 15);
  const int row0 = m0 + wm + ((lane >> 4) << 2);
  if (MODE == 1) {
#pragma unroll
    for (int ni = 0; ni < 4; ++ni) {
      const int n = col0 + ni * 16;
      const float bv = bias_q[n];  // bo
#pragma unroll
      for (int mi = 0; mi < 4; ++mi) {
        const int mrow = row0 + mi * 16;
#pragma unroll
        for (int r = 0; r < 4; ++r)
          outf[(size_t)(mrow + r) * 1024 + n] = acc[mi][ni][r] + bv;
      }
    }
  } else {
#pragma unroll
    for (int ni = 0; ni < 4; ++ni) {
      const int n = col0 + ni * 16;
      const int sect = n >> 10, h = (n >> 6) & 15, dd = n & 63;
      float bv;
      if (sect == 0) bv = bias_q[h * 64 + dd] * QSCALE;
      else if (sect == 1) bv = bias_k[h * 64 + dd];
      else bv = bias_v[h * 64 + dd];
#pragma unroll
      for (int mi = 0; mi < 4; ++mi) {
        const int mrow = row0 + mi * 16;
        const int b = mrow >> 11, s = mrow & 2047;
        const int bh = b * 16 + h;
        if (sect == 2) {
          u16x4 pk;
#pragma unroll
          for (int r = 0; r < 4; ++r) pk[r] = f2bf(acc[mi][ni][r] + bv);
          *(u16x4*)(Vtws + ((size_t)bh * 64 + dd) * 2048 + s) = pk;  // V^T [bh][d][s]
        } else {
          uint16_t* dst = (sect == 0 ? Qws : Kws) + ((size_t)bh * 2048 + s) * 64 + dd;
#pragma unroll
          for (int r = 0; r < 4; ++r) dst[(size_t)r * 64] = f2bf(acc[mi][ni][r] + bv);
        }
      }
    }
  }
}

// ---------------- flash attention (swapped-QK^T, 32x32 MFMA, in-reg softmax) ----
// grid: bh(64) x qtile(16); block 256 = 4 waves, each wave owns 32 q-rows.
__global__ __launch_bounds__(256, 2) void attn_fa(
    const uint16_t* __restrict__ Qws, const uint16_t* __restrict__ Kws,
    const uint16_t* __restrict__ Vtws, uint16_t* __restrict__ AttO) {
  __shared__ uint16_t Kl[2][64 * 64];  // [kv][d], dbuf
  __shared__ uint16_t Vl[2][64 * 64];  // V^T [d][kv], dbuf

  const int tid = threadIdx.x, lane = tid & 63, wq = tid >> 6;
  const int bh = blockIdx.x >> 4;
  const int q0 = (blockIdx.x & 15) * 128;
  const int hi = lane >> 5;   // lane half
  const int qc = lane & 31;   // col index (q for S/O; also kv/d row for A-frags)

  const uint16_t* Qb = Qws + (size_t)bh * (2048 * 64);
  const uint16_t* Kb = Kws + (size_t)bh * (2048 * 64);
  const uint16_t* Vb = Vtws + (size_t)bh * (64 * 2048);

  // staging indices: 256 threads stage a 64x64 bf16 tile in 2 shots of 16B/thread
  const int lrow = lane >> 3;                       // 0..7
  const int csw = ((lane & 7) ^ lrow) * 16;         // pre-swizzled source chunk

  // Q B-frags (col=q=qc, k=d=16c+8hi+j), held in registers for the whole block
  short8 qf[4];
  const int qrow = q0 + wq * 32 + qc;
#pragma unroll
  for (int c = 0; c < 4; ++c)
    qf[c] = *(const short8*)(Qb + (size_t)qrow * 64 + c * 16 + hi * 8);

  f32x16 o0 = {}, o1 = {};  // O^T acc: rows d = 32*no + crow(r,hi), col q = qc
  float m = 8.0f, l = 0.0f;

  auto stage = [&](int buf, int kt) {
    const int kv0 = kt * 64;
#pragma unroll
    for (int i = 0; i < 2; ++i) {
      const int rb = i * 32 + wq * 8;   // wave-uniform row base
      const int rt = rb + lrow;         // this lane's source row
      gload_lds16((const char*)Kb + (size_t)(kv0 + rt) * 128 + csw,
                  (char*)&Kl[buf][0] + rb * 128);
      gload_lds16((const char*)Vb + ((size_t)rt * 2048 + kv0) * 2 + csw,
                  (char*)&Vl[buf][0] + rb * 128);
    }
  };

  stage(0, 0);
  for (int kt = 0; kt < 32; ++kt) {
    const int buf = kt & 1;
    __syncthreads();  // staging of buf complete
    if (kt + 1 < 32) stage(buf ^ 1, kt + 1);

    // S^T = K · Q^T : p[km] holds S[kv=32km+crow(r,hi)][q=qc]  (log2 units)
    f32x16 p0 = {}, p1 = {};
    __builtin_amdgcn_s_setprio(1);
#pragma unroll
    for (int c = 0; c < 4; ++c) {
      short8 k0 = lds_frag(&Kl[buf][0], qc, c * 32 + hi * 16);
      short8 k1 = lds_frag(&Kl[buf][0], 32 + qc, c * 32 + hi * 16);
      p0 = mfma32(k0, qf[c], p0);
      p1 = mfma32(k1, qf[c], p1);
    }
    __builtin_amdgcn_s_setprio(0);

    // ---- in-register online softmax (per lane: one q, 32 kv values) ----
    float mx = p0[0];
#pragma unroll
    for (int r = 1; r < 16; ++r) mx = fmaxf(mx, p0[r]);
#pragma unroll
    for (int r = 0; r < 16; ++r) mx = fmaxf(mx, p1[r]);
    mx = fmaxf(mx, __shfl_xor(mx, 32, 64));  // full row: lanes q and q+32
    if (__any(mx - m > 8.0f)) {              // defer-max (T13), wave-uniform
      const float nm = fmaxf(m, mx);
      const float al = __builtin_amdgcn_exp2f(m - nm);
      l *= al;
#pragma unroll
      for (int r = 0; r < 16; ++r) { o0[r] *= al; o1[r] *= al; }
      m = nm;
    }
    float sum = 0.f;
#pragma unroll
    for (int r = 0; r < 16; ++r) { p0[r] = __builtin_amdgcn_exp2f(p0[r] - m); sum += p0[r]; }
#pragma unroll
    for (int r = 0; r < 16; ++r) { p1[r] = __builtin_amdgcn_exp2f(p1[r] - m); sum += p1[r]; }
    sum += __shfl_xor(sum, 32, 64);
    l += sum;

    // ---- P^T -> PV B-frags in-register (T12: cvt_pk + permlane32_swap) ----
    // value p[km][r] sits at kv-bits: b0b1=r&3, b2=hi, b3b4=r>>2, b5=km.
    // target frag pa[ks]: lane needs kv = 16*ks + 8*hi_t + j  (j=b0b1b2).
    short8 pa[4];
#pragma unroll
    for (int km = 0; km < 2; ++km) {
#pragma unroll
      for (int bb = 0; bb < 2; ++bb) {
        const f32x16& p = km ? p1 : p0;
        uint32_t X0 = cvtpk(p[8 * bb + 0], p[8 * bb + 1]);
        uint32_t Y0 = cvtpk(p[8 * bb + 4], p[8 * bb + 5]);
        uint32_t X1 = cvtpk(p[8 * bb + 2], p[8 * bb + 3]);
        uint32_t Y1 = cvtpk(p[8 * bb + 6], p[8 * bb + 7]);
        i32x2 s0 = __builtin_amdgcn_permlane32_swap((int)X0, (int)Y0, false, false);
        i32x2 s1 = __builtin_amdgcn_permlane32_swap((int)X1, (int)Y1, false, false);
        u32x4 dw = {(uint32_t)s0[0], (uint32_t)s1[0], (uint32_t)s0[1], (uint32_t)s1[1]};
        pa[km * 2 + bb] = __builtin_bit_cast(short8, dw);
      }
    }

    // ---- O^T += V^T · P^T ----
    __builtin_amdgcn_s_setprio(1);
#pragma unroll
    for (int ks = 0; ks < 4; ++ks) {
      short8 v0 = lds_frag(&Vl[buf][0], qc, ks * 32 + hi * 16);
      short8 v1 = lds_frag(&Vl[buf][0], 32 + qc, ks * 32 + hi * 16);
      o0 = mfma32(v0, pa[ks], o0);
      o1 = mfma32(v1, pa[ks], o1);
    }
    __builtin_amdgcn_s_setprio(0);
    __syncthreads();  // all waves done with buf before it is re-staged
  }

  // ---- epilogue: normalize, transpose via LDS (reuse Kl), coalesced store ----
  const float inv = 1.0f / l;
#pragma unroll
  for (int r = 0; r < 16; ++r) { o0[r] *= inv; o1[r] *= inv; }

  uint16_t* ep = (uint16_t*)Kl + wq * 2048;  // 4KB region per wave
#pragma unroll
  for (int no = 0; no < 2; ++no)
#pragma unroll
    for (int rg = 0; rg < 4; ++rg) {
      const f32x16& oo = no ? o1 : o0;
      const int d0 = no * 32 + rg * 8 + hi * 4;  // 4 consecutive d per group
      u16x4 pk;
#pragma unroll
      for (int j = 0; j < 4; ++j) pk[j] = f2bf(oo[rg * 4 + j]);
      *(u16x4*)((char*)ep + qc * 128 + ((d0 * 2) ^ ((qc & 7) << 4))) = pk;
    }
  // own-region read-back (no barrier needed: each wave reads only its own writes)
  const int b = bh >> 4, h = bh & 15;
#pragma unroll
  for (int it = 0; it < 4; ++it) {
    const int pos = it * 64 + lane;
    const int qq = pos >> 3, c = pos & 7;
    short8 vv = *(const short8*)((const char*)ep + qq * 128 + ((c * 16) ^ ((qq & 7) << 4)));
    *(short8*)(AttO + ((size_t)b * 2048 + q0 + wq * 32 + qq) * 1024 + h * 64 + c * 8) = vv;
  }
}

// ---------------- launcher ----------------

extern "C" void kernel_launch(void* const* d_in, const int* in_sizes, int n_in,
                              void* d_out, int out_size, void* d_ws, size_t ws_size,
                              hipStream_t stream) {
  (void)in_sizes; (void)n_in; (void)out_size; (void)ws_size;
  const float* x  = (const float*)d_in[0];
  const float* Wq = (const float*)d_in[1];
  const float* bq = (const float*)d_in[2];
  const float* Wk = (const float*)d_in[3];
  const float* bk = (const float*)d_in[4];
  const float* Wv = (const float*)d_in[5];
  const float* bv = (const float*)d_in[6];
  const float* Wo = (const float*)d_in[7];
  const float* bo = (const float*)d_in[8];
  float* out = (float*)d_out;

  char* ws = (char*)d_ws;
  uint16_t* Xb   = (uint16_t*)(ws);                 // [8192][1024] bf16
  uint16_t* AttO = (uint16_t*)(ws);                 // alias (Xb dead after GEMM1)
  uint16_t* Wqkv = (uint16_t*)(ws + 16777216);      // [3072][1024] bf16
  uint16_t* Wob  = (uint16_t*)(ws + 23068672);      // [1024][1024] bf16
  uint16_t* Qws  = (uint16_t*)(ws + 25165824);      // [64][2048][64] bf16
  uint16_t* Kws  = (uint16_t*)(ws + 41943040);      // [64][2048][64] bf16
  uint16_t* Vt   = (uint16_t*)(ws + 58720256);      // [64][64][2048] bf16

  k_cvt_x<<<4096, 256, 0, stream>>>(x, Xb);
  k_cvt_wqkv<<<768, 256, 0, stream>>>(Wq, Wk, Wv, Wqkv);
  k_cvt_wo<<<512, 256, 0, stream>>>(Wo, Wob);
  gemm_k1024<0><<<64 * 24, 256, 0, stream>>>(Xb, Wqkv, 24, bq, bk, bv, Qws, Kws, Vt, nullptr);
  attn_fa<<<1024, 256, 0, stream>>>(Qws, Kws, Vt, AttO);
  gemm_k1024<1><<<64 * 8, 256, 0, stream>>>(AttO, Wob, 8, bo, nullptr, nullptr,
                                            nullptr, nullptr, nullptr, out);
}

// Round 3
// 199.086 us; speedup vs baseline: 1.6036x; 1.0224x over previous
//
#include <hip/hip_runtime.h>
#include <stdint.h>

#define DEVI __device__ __forceinline__

typedef float f32x4 __attribute__((ext_vector_type(4)));
typedef float f32x16 __attribute__((ext_vector_type(16)));
typedef float float4v __attribute__((ext_vector_type(4)));
typedef short short8 __attribute__((ext_vector_type(8)));
typedef uint16_t u16x4 __attribute__((ext_vector_type(4)));
typedef uint32_t u32x4 __attribute__((ext_vector_type(4)));
typedef int i32x2 __attribute__((ext_vector_type(2)));

// fold softmax scale (1/sqrt(64)) and log2(e) into Q so softmax uses exp2
static constexpr float QSCALE = 0.125f * 1.44269504088896340736f;

DEVI uint16_t f2bf(float f) {
  uint32_t u = __builtin_bit_cast(uint32_t, f);
  return (uint16_t)((u + 0x7FFFu + ((u >> 16) & 1u)) >> 16);  // RNE
}

DEVI void gload_lds16(const void* g, void* lds) {
  __builtin_amdgcn_global_load_lds(
      reinterpret_cast<const uint32_t __attribute__((address_space(1)))*>(
          reinterpret_cast<uintptr_t>(g)),
      reinterpret_cast<uint32_t __attribute__((address_space(3)))*>(
          reinterpret_cast<uintptr_t>(lds)),
      16, 0, 0);
}

// swizzled read of a bf16x8 fragment from a [rows][64] bf16 LDS tile (128B rows)
// swizzle: byte ^= (row&7)<<4  (matches pre-swizzled global_load_lds source)
DEVI short8 lds_frag(const uint16_t* tile, int row, int kByte) {
  return *(const short8*)((const char*)tile + row * 128 + (kByte ^ ((row & 7) << 4)));
}

DEVI f32x4 mfma16(short8 a, short8 b, f32x4 c) {
  return __builtin_amdgcn_mfma_f32_16x16x32_bf16(a, b, c, 0, 0, 0);
}
DEVI f32x16 mfma32(short8 a, short8 b, f32x16 c) {
  return __builtin_amdgcn_mfma_f32_32x32x16_bf16(a, b, c, 0, 0, 0);
}

DEVI uint32_t cvtpk(float lo, float hi) {
  uint32_t r;
  asm("v_cvt_pk_bf16_f32 %0, %1, %2" : "=v"(r) : "v"(lo), "v"(hi));
  return r;
}

// ---------------- prep kernels ----------------

__global__ void k_cvt_x(const float* __restrict__ x, uint16_t* __restrict__ xb) {
  const int i = blockIdx.x * blockDim.x + threadIdx.x;  // 8-elem chunks
  const float4v* p = (const float4v*)x + (size_t)i * 2;
  float4v a = p[0], b = p[1];
  alignas(16) uint16_t r[8];
  r[0] = f2bf(a[0]); r[1] = f2bf(a[1]); r[2] = f2bf(a[2]); r[3] = f2bf(a[3]);
  r[4] = f2bf(b[0]); r[5] = f2bf(b[1]); r[6] = f2bf(b[2]); r[7] = f2bf(b[3]);
  *((short8*)xb + i) = *(const short8*)r;
}

__global__ void k_cvt_wo(const float* __restrict__ Wo, uint16_t* __restrict__ Wob) {
  const int i = blockIdx.x * blockDim.x + threadIdx.x;
  const float4v* p = (const float4v*)Wo + (size_t)i * 2;
  float4v a = p[0], b = p[1];
  alignas(16) uint16_t r[8];
  r[0] = f2bf(a[0]); r[1] = f2bf(a[1]); r[2] = f2bf(a[2]); r[3] = f2bf(a[3]);
  r[4] = f2bf(b[0]); r[5] = f2bf(b[1]); r[6] = f2bf(b[2]); r[7] = f2bf(b[3]);
  *((short8*)Wob + i) = *(const short8*)r;
}

// Build Wqkv_t [N=3072][K=1024] bf16 where row n = (sect,h,dd):
//   Wt[n][k] = Wsect[h][k][dd]   (transpose via LDS tile, coalesced both sides)
__global__ void k_cvt_wqkv(const float* __restrict__ Wq, const float* __restrict__ Wk,
                           const float* __restrict__ Wv, uint16_t* __restrict__ Wt) {
  __shared__ float tile[64][65];
  const int bx = blockIdx.x;
  const int sect = bx >> 8, h = (bx >> 4) & 15, kc = bx & 15;
  const float* W = sect == 0 ? Wq : (sect == 1 ? Wk : Wv);
  const float scal = sect == 0 ? QSCALE : 1.0f;
  const int t = threadIdx.x;
  const int r = t >> 2, cbase = (t & 3) * 16;
  const float* src = W + ((size_t)(h * 1024 + kc * 64 + r)) * 64 + cbase;
#pragma unroll
  for (int j = 0; j < 4; ++j) {
    float4v v = *(const float4v*)(src + j * 4);
    tile[r][cbase + j * 4 + 0] = v[0];
    tile[r][cbase + j * 4 + 1] = v[1];
    tile[r][cbase + j * 4 + 2] = v[2];
    tile[r][cbase + j * 4 + 3] = v[3];
  }
  __syncthreads();
  const int dd = t >> 2, kp = (t & 3) * 16;
  alignas(16) uint16_t tmp[16];
#pragma unroll
  for (int j = 0; j < 16; ++j) tmp[j] = f2bf(tile[kp + j][dd] * scal);
  const int n = sect * 1024 + h * 64 + dd;
  uint16_t* dst = Wt + (size_t)n * 1024 + kc * 64 + kp;
  *(short8*)dst = *(const short8*)tmp;
  *((short8*)dst + 1) = *(const short8*)(tmp + 8);
}

// ---------------- GEMM (K=1024, 128x128 tile, BK=64, dbuf LDS) ----------------
template <int MODE>
__global__ __launch_bounds__(256, 2) void gemm_k1024(
    const uint16_t* __restrict__ A, const uint16_t* __restrict__ Bt, int tiles_n,
    const float* __restrict__ bias_q, const float* __restrict__ bias_k,
    const float* __restrict__ bias_v,
    uint16_t* __restrict__ Qws, uint16_t* __restrict__ Kws, uint16_t* __restrict__ Vtws,
    float* __restrict__ outf) {
  __shared__ uint16_t As[2][128 * 64];
  __shared__ uint16_t Bs[2][128 * 64];

  const int tid = threadIdx.x, lane = tid & 63, wv = tid >> 6;
  const int m0 = (blockIdx.x / tiles_n) * 128;
  const int n0 = (blockIdx.x % tiles_n) * 128;
  const int wm = (wv >> 1) * 64, wn = (wv & 1) * 64;
  const int rin = lane >> 3;
  const int csw = ((lane & 7) ^ rin) * 16;

  const char* gA = (const char*)A;
  const char* gB = (const char*)Bt;

  f32x4 acc[4][4];
#pragma unroll
  for (int mi = 0; mi < 4; ++mi)
#pragma unroll
    for (int ni = 0; ni < 4; ++ni) acc[mi][ni] = (f32x4){0.f, 0.f, 0.f, 0.f};

  auto stage = [&](int buf, int kt) {
    const int k0b = kt * 128;
#pragma unroll
    for (int i = 0; i < 4; ++i) {
      const int rb = wv * 32 + i * 8;
      gload_lds16(gA + (size_t)(m0 + rb + rin) * 2048 + k0b + csw, &As[buf][rb * 64]);
      gload_lds16(gB + (size_t)(n0 + rb + rin) * 2048 + k0b + csw, &Bs[buf][rb * 64]);
    }
  };

  stage(0, 0);
  const int kb0 = (lane >> 4) * 16;
  for (int kt = 0; kt < 16; ++kt) {
    const int buf = kt & 1;
    // single barrier per iter: also guarantees prior iter's readers finished
    // before this iter's stage overwrites their buffer (all-arrive semantics).
    __syncthreads();
    if (kt + 1 < 16) stage(buf ^ 1, kt + 1);
#pragma unroll
    for (int kk = 0; kk < 2; ++kk) {
      short8 af[4], bfr[4];
#pragma unroll
      for (int i = 0; i < 4; ++i) {
        af[i] = lds_frag(As[buf], wm + i * 16 + (lane & 15), kk * 64 + kb0);
        bfr[i] = lds_frag(Bs[buf], wn + i * 16 + (lane & 15), kk * 64 + kb0);
      }
#pragma unroll
      for (int mi = 0; mi < 4; ++mi)
#pragma unroll
        for (int ni = 0; ni < 4; ++ni) acc[mi][ni] = mfma16(af[mi], bfr[ni], acc[mi][ni]);
    }
  }

  const int col0 = n0 + wn + (lane & 15);
  const int row0 = m0 + wm + ((lane >> 4) << 2);
  if (MODE == 1) {
#pragma unroll
    for (int ni = 0; ni < 4; ++ni) {
      const int n = col0 + ni * 16;
      const float bv = bias_q[n];  // bo
#pragma unroll
      for (int mi = 0; mi < 4; ++mi) {
        const int mrow = row0 + mi * 16;
#pragma unroll
        for (int r = 0; r < 4; ++r)
          outf[(size_t)(mrow + r) * 1024 + n] = acc[mi][ni][r] + bv;
      }
    }
  } else {
#pragma unroll
    for (int ni = 0; ni < 4; ++ni) {
      const int n = col0 + ni * 16;
      const int sect = n >> 10, h = (n >> 6) & 15, dd = n & 63;
      float bv;
      if (sect == 0) bv = bias_q[h * 64 + dd] * QSCALE;
      else if (sect == 1) bv = bias_k[h * 64 + dd];
      else bv = bias_v[h * 64 + dd];
#pragma unroll
      for (int mi = 0; mi < 4; ++mi) {
        const int mrow = row0 + mi * 16;
        const int b = mrow >> 11, s = mrow & 2047;
        const int bh = b * 16 + h;
        if (sect == 2) {
          u16x4 pk;
#pragma unroll
          for (int r = 0; r < 4; ++r) pk[r] = f2bf(acc[mi][ni][r] + bv);
          *(u16x4*)(Vtws + ((size_t)bh * 64 + dd) * 2048 + s) = pk;  // V^T [bh][d][s]
        } else {
          uint16_t* dst = (sect == 0 ? Qws : Kws) + ((size_t)bh * 2048 + s) * 64 + dd;
#pragma unroll
          for (int r = 0; r < 4; ++r) dst[(size_t)r * 64] = f2bf(acc[mi][ni][r] + bv);
        }
      }
    }
  }
}

// ---------------- flash attention (swapped-QK^T, 32x32 MFMA, in-reg softmax) ----
// grid: 1024 blocks; XCD-swizzled so all 16 q-tiles of one bh land on one XCD
// (8 bh per XCD -> K/V working set 8*512KB = 4MB = one L2). 4 waves/block.
__global__ __launch_bounds__(256, 2) void attn_fa(
    const uint16_t* __restrict__ Qws, const uint16_t* __restrict__ Kws,
    const uint16_t* __restrict__ Vtws, uint16_t* __restrict__ AttO) {
  __shared__ uint16_t Kl[2][64 * 64];  // [kv][d], dbuf
  __shared__ uint16_t Vl[2][64 * 64];  // V^T [d][kv], dbuf

  const int tid = threadIdx.x, lane = tid & 63, wq = tid >> 6;
  // XCD-aware decode: default dispatch round-robins bid%8 across XCDs.
  const int bid = blockIdx.x;
  const int bh = (bid & 7) * 8 + (bid >> 7);        // (bid>>3)>>4
  const int q0 = ((bid >> 3) & 15) * 128;
  const int hi = lane >> 5;   // lane half
  const int qc = lane & 31;   // col index (q for S/O; also kv/d row for A-frags)

  const uint16_t* Qb = Qws + (size_t)bh * (2048 * 64);
  const uint16_t* Kb = Kws + (size_t)bh * (2048 * 64);
  const uint16_t* Vb = Vtws + (size_t)bh * (64 * 2048);

  // staging indices: 256 threads stage a 64x64 bf16 tile in 2 shots of 16B/thread
  const int lrow = lane >> 3;                       // 0..7
  const int csw = ((lane & 7) ^ lrow) * 16;         // pre-swizzled source chunk

  // Q B-frags (col=q=qc, k=d=16c+8hi+j), held in registers for the whole block
  short8 qf[4];
  const int qrow = q0 + wq * 32 + qc;
#pragma unroll
  for (int c = 0; c < 4; ++c)
    qf[c] = *(const short8*)(Qb + (size_t)qrow * 64 + c * 16 + hi * 8);

  short8 ones;
#pragma unroll
  for (int j = 0; j < 8; ++j) ones[j] = (short)0x3F80;  // bf16 1.0

  f32x16 o0 = {}, o1 = {};   // O^T acc: rows d = 32*no + crow(r,hi), col q = qc
  f32x16 accL = {};          // ones-row trick: accL[0] = running sum l (col q=qc)
  float m = 8.0f;

  auto stage = [&](int buf, int kt) {
    const int kv0 = kt * 64;
#pragma unroll
    for (int i = 0; i < 2; ++i) {
      const int rb = i * 32 + wq * 8;   // wave-uniform row base
      const int rt = rb + lrow;         // this lane's source row
      gload_lds16((const char*)Kb + (size_t)(kv0 + rt) * 128 + csw,
                  (char*)&Kl[buf][0] + rb * 128);
      gload_lds16((const char*)Vb + ((size_t)rt * 2048 + kv0) * 2 + csw,
                  (char*)&Vl[buf][0] + rb * 128);
    }
  };

  stage(0, 0);
  for (int kt = 0; kt < 32; ++kt) {
    const int buf = kt & 1;
    __syncthreads();  // staging of buf complete; prior readers of buf^1 done
    if (kt + 1 < 32) stage(buf ^ 1, kt + 1);

    // S^T = K · Q^T : p[km] holds S[kv=32km+crow(r,hi)][q=qc]  (log2 units)
    f32x16 p0 = {}, p1 = {};
    __builtin_amdgcn_s_setprio(1);
#pragma unroll
    for (int c = 0; c < 4; ++c) {
      short8 k0 = lds_frag(&Kl[buf][0], qc, c * 32 + hi * 16);
      short8 k1 = lds_frag(&Kl[buf][0], 32 + qc, c * 32 + hi * 16);
      p0 = mfma32(k0, qf[c], p0);
      p1 = mfma32(k1, qf[c], p1);
    }
    __builtin_amdgcn_s_setprio(0);

    // ---- in-register online softmax (per lane: one q, 32 kv values) ----
    // tree max (depth 5, max3-fusable) instead of a 31-op serial chain
    float t8[8];
#pragma unroll
    for (int r = 0; r < 8; ++r)
      t8[r] = fmaxf(fmaxf(p0[2 * r], p0[2 * r + 1]),
                    fmaxf(p1[2 * r], p1[2 * r + 1]));
#pragma unroll
    for (int r = 0; r < 4; ++r) t8[r] = fmaxf(t8[r], t8[r + 4]);
    float mx = fmaxf(fmaxf(t8[0], t8[1]), fmaxf(t8[2], t8[3]));
    mx = fmaxf(mx, __shfl_xor(mx, 32, 64));  // full row: lanes q and q+32
    if (__any(mx - m > 8.0f)) {              // defer-max (T13), wave-uniform
      const float nm = fmaxf(m, mx);
      const float al = __builtin_amdgcn_exp2f(m - nm);
      accL[0] *= al;                         // only element 0 of accL is ever read
#pragma unroll
      for (int r = 0; r < 16; ++r) { o0[r] *= al; o1[r] *= al; }
      m = nm;
    }
#pragma unroll
    for (int r = 0; r < 16; ++r) p0[r] = __builtin_amdgcn_exp2f(p0[r] - m);
#pragma unroll
    for (int r = 0; r < 16; ++r) p1[r] = __builtin_amdgcn_exp2f(p1[r] - m);

    // ---- P^T -> PV B-frags in-register (T12: cvt_pk + permlane32_swap) ----
    // value p[km][r] sits at kv-bits: b0b1=r&3, b2=hi, b3b4=r>>2, b5=km.
    // target frag pa[ks]: lane needs kv = 16*ks + 8*hi_t + j  (j=b0b1b2).
    short8 pa[4];
#pragma unroll
    for (int km = 0; km < 2; ++km) {
#pragma unroll
      for (int bb = 0; bb < 2; ++bb) {
        const f32x16& p = km ? p1 : p0;
        uint32_t X0 = cvtpk(p[8 * bb + 0], p[8 * bb + 1]);
        uint32_t Y0 = cvtpk(p[8 * bb + 4], p[8 * bb + 5]);
        uint32_t X1 = cvtpk(p[8 * bb + 2], p[8 * bb + 3]);
        uint32_t Y1 = cvtpk(p[8 * bb + 6], p[8 * bb + 7]);
        i32x2 s0 = __builtin_amdgcn_permlane32_swap((int)X0, (int)Y0, false, false);
        i32x2 s1 = __builtin_amdgcn_permlane32_swap((int)X1, (int)Y1, false, false);
        u32x4 dw = {(uint32_t)s0[0], (uint32_t)s1[0], (uint32_t)s0[1], (uint32_t)s1[1]};
        pa[km * 2 + bb] = __builtin_bit_cast(short8, dw);
      }
    }

    // ---- O^T += V^T · P^T ;  l += row-sum via ones-A MFMA (frees 32 VALU adds) ----
    __builtin_amdgcn_s_setprio(1);
#pragma unroll
    for (int ks = 0; ks < 4; ++ks) {
      short8 v0 = lds_frag(&Vl[buf][0], qc, ks * 32 + hi * 16);
      short8 v1 = lds_frag(&Vl[buf][0], 32 + qc, ks * 32 + hi * 16);
      o0 = mfma32(v0, pa[ks], o0);
      o1 = mfma32(v1, pa[ks], o1);
      accL = mfma32(ones, pa[ks], accL);
    }
    __builtin_amdgcn_s_setprio(0);
    // no second barrier: next iter's top barrier provides the WAR protection
  }
  __syncthreads();  // protect epilogue reuse of Kl against other waves' last reads

  // ---- epilogue: normalize, transpose via LDS (reuse Kl), coalesced store ----
  const float inv = 1.0f / accL[0];
#pragma unroll
  for (int r = 0; r < 16; ++r) { o0[r] *= inv; o1[r] *= inv; }

  uint16_t* ep = (uint16_t*)Kl + wq * 2048;  // 4KB region per wave
#pragma unroll
  for (int no = 0; no < 2; ++no)
#pragma unroll
    for (int rg = 0; rg < 4; ++rg) {
      const f32x16& oo = no ? o1 : o0;
      const int d0 = no * 32 + rg * 8 + hi * 4;  // 4 consecutive d per group
      u16x4 pk;
#pragma unroll
      for (int j = 0; j < 4; ++j) pk[j] = f2bf(oo[rg * 4 + j]);
      *(u16x4*)((char*)ep + qc * 128 + ((d0 * 2) ^ ((qc & 7) << 4))) = pk;
    }
  // own-region read-back (no barrier needed: each wave reads only its own writes)
  const int b = bh >> 4, h = bh & 15;
#pragma unroll
  for (int it = 0; it < 4; ++it) {
    const int pos = it * 64 + lane;
    const int qq = pos >> 3, c = pos & 7;
    short8 vv = *(const short8*)((const char*)ep + qq * 128 + ((c * 16) ^ ((qq & 7) << 4)));
    *(short8*)(AttO + ((size_t)b * 2048 + q0 + wq * 32 + qq) * 1024 + h * 64 + c * 8) = vv;
  }
}

// ---------------- launcher ----------------

extern "C" void kernel_launch(void* const* d_in, const int* in_sizes, int n_in,
                              void* d_out, int out_size, void* d_ws, size_t ws_size,
                              hipStream_t stream) {
  (void)in_sizes; (void)n_in; (void)out_size; (void)ws_size;
  const float* x  = (const float*)d_in[0];
  const float* Wq = (const float*)d_in[1];
  const float* bq = (const float*)d_in[2];
  const float* Wk = (const float*)d_in[3];
  const float* bk = (const float*)d_in[4];
  const float* Wv = (const float*)d_in[5];
  const float* bv = (const float*)d_in[6];
  const float* Wo = (const float*)d_in[7];
  const float* bo = (const float*)d_in[8];
  float* out = (float*)d_out;

  char* ws = (char*)d_ws;
  uint16_t* Xb   = (uint16_t*)(ws);                 // [8192][1024] bf16
  uint16_t* AttO = (uint16_t*)(ws);                 // alias (Xb dead after GEMM1)
  uint16_t* Wqkv = (uint16_t*)(ws + 16777216);      // [3072][1024] bf16
  uint16_t* Wob  = (uint16_t*)(ws + 23068672);      // [1024][1024] bf16
  uint16_t* Qws  = (uint16_t*)(ws + 25165824);      // [64][2048][64] bf16
  uint16_t* Kws  = (uint16_t*)(ws + 41943040);      // [64][2048][64] bf16
  uint16_t* Vt   = (uint16_t*)(ws + 58720256);      // [64][64][2048] bf16

  k_cvt_x<<<4096, 256, 0, stream>>>(x, Xb);
  k_cvt_wqkv<<<768, 256, 0, stream>>>(Wq, Wk, Wv, Wqkv);
  k_cvt_wo<<<512, 256, 0, stream>>>(Wo, Wob);
  gemm_k1024<0><<<64 * 24, 256, 0, stream>>>(Xb, Wqkv, 24, bq, bk, bv, Qws, Kws, Vt, nullptr);
  attn_fa<<<1024, 256, 0, stream>>>(Qws, Kws, Vt, AttO);
  gemm_k1024<1><<<64 * 8, 256, 0, stream>>>(AttO, Wob, 8, bo, nullptr, nullptr,
                                            nullptr, nullptr, nullptr, out);
}

// Round 4
// 190.361 us; speedup vs baseline: 1.6770x; 1.0458x over previous
//
#include <hip/hip_runtime.h>
#include <stdint.h>

#define DEVI __device__ __forceinline__

typedef float f32x4 __attribute__((ext_vector_type(4)));
typedef float f32x16 __attribute__((ext_vector_type(16)));
typedef float float4v __attribute__((ext_vector_type(4)));
typedef short short8 __attribute__((ext_vector_type(8)));
typedef uint16_t u16x4 __attribute__((ext_vector_type(4)));
typedef uint32_t u32x4 __attribute__((ext_vector_type(4)));
typedef int i32x2 __attribute__((ext_vector_type(2)));

// fold softmax scale (1/sqrt(64)) and log2(e) into Q so softmax uses exp2
static constexpr float QSCALE = 0.125f * 1.44269504088896340736f;

DEVI uint16_t f2bf(float f) {
  uint32_t u = __builtin_bit_cast(uint32_t, f);
  return (uint16_t)((u + 0x7FFFu + ((u >> 16) & 1u)) >> 16);  // RNE
}

DEVI void gload_lds16(const void* g, void* lds) {
  __builtin_amdgcn_global_load_lds(
      reinterpret_cast<const uint32_t __attribute__((address_space(1)))*>(
          reinterpret_cast<uintptr_t>(g)),
      reinterpret_cast<uint32_t __attribute__((address_space(3)))*>(
          reinterpret_cast<uintptr_t>(lds)),
      16, 0, 0);
}

// swizzled read of a bf16x8 fragment from a [rows][64] bf16 LDS tile (128B rows)
// swizzle: byte ^= (row&7)<<4  (matches pre-swizzled global_load_lds source)
DEVI short8 lds_frag(const uint16_t* tile, int row, int kByte) {
  return *(const short8*)((const char*)tile + row * 128 + (kByte ^ ((row & 7) << 4)));
}

DEVI f32x4 mfma16(short8 a, short8 b, f32x4 c) {
  return __builtin_amdgcn_mfma_f32_16x16x32_bf16(a, b, c, 0, 0, 0);
}
DEVI f32x16 mfma32(short8 a, short8 b, f32x16 c) {
  return __builtin_amdgcn_mfma_f32_32x32x16_bf16(a, b, c, 0, 0, 0);
}

DEVI uint32_t cvtpk(float lo, float hi) {
  uint32_t r;
  asm("v_cvt_pk_bf16_f32 %0, %1, %2" : "=v"(r) : "v"(lo), "v"(hi));
  return r;
}

// P^T -> PV B-frags in-register (T12: cvt_pk + permlane32_swap)
// value p[km][r] sits at kv-bits: b0b1=r&3, b2=hi, b3b4=r>>2, b5=km.
// target frag pa[ks]: lane needs kv = 16*ks + 8*hi_t + j  (j=b0b1b2).
DEVI void mk_pa(const f32x16& p0, const f32x16& p1, short8* pa) {
#pragma unroll
  for (int km = 0; km < 2; ++km) {
#pragma unroll
    for (int bb = 0; bb < 2; ++bb) {
      const f32x16& p = km ? p1 : p0;
      uint32_t X0 = cvtpk(p[8 * bb + 0], p[8 * bb + 1]);
      uint32_t Y0 = cvtpk(p[8 * bb + 4], p[8 * bb + 5]);
      uint32_t X1 = cvtpk(p[8 * bb + 2], p[8 * bb + 3]);
      uint32_t Y1 = cvtpk(p[8 * bb + 6], p[8 * bb + 7]);
      i32x2 s0 = __builtin_amdgcn_permlane32_swap((int)X0, (int)Y0, false, false);
      i32x2 s1 = __builtin_amdgcn_permlane32_swap((int)X1, (int)Y1, false, false);
      u32x4 dw = {(uint32_t)s0[0], (uint32_t)s1[0], (uint32_t)s0[1], (uint32_t)s1[1]};
      pa[km * 2 + bb] = __builtin_bit_cast(short8, dw);
    }
  }
}

// tree max of the 32 values in p0,p1 (max3-fusable)
DEVI float tree_max(const f32x16& p0, const f32x16& p1) {
  float t8[8];
#pragma unroll
  for (int r = 0; r < 8; ++r)
    t8[r] = fmaxf(fmaxf(p0[2 * r], p0[2 * r + 1]),
                  fmaxf(p1[2 * r], p1[2 * r + 1]));
#pragma unroll
  for (int r = 0; r < 4; ++r) t8[r] = fmaxf(t8[r], t8[r + 4]);
  return fmaxf(fmaxf(t8[0], t8[1]), fmaxf(t8[2], t8[3]));
}

// ---------------- prep kernels ----------------

__global__ void k_cvt_x(const float* __restrict__ x, uint16_t* __restrict__ xb) {
  const int i = blockIdx.x * blockDim.x + threadIdx.x;  // 8-elem chunks
  const float4v* p = (const float4v*)x + (size_t)i * 2;
  float4v a = p[0], b = p[1];
  alignas(16) uint16_t r[8];
  r[0] = f2bf(a[0]); r[1] = f2bf(a[1]); r[2] = f2bf(a[2]); r[3] = f2bf(a[3]);
  r[4] = f2bf(b[0]); r[5] = f2bf(b[1]); r[6] = f2bf(b[2]); r[7] = f2bf(b[3]);
  *((short8*)xb + i) = *(const short8*)r;
}

__global__ void k_cvt_wo(const float* __restrict__ Wo, uint16_t* __restrict__ Wob) {
  const int i = blockIdx.x * blockDim.x + threadIdx.x;
  const float4v* p = (const float4v*)Wo + (size_t)i * 2;
  float4v a = p[0], b = p[1];
  alignas(16) uint16_t r[8];
  r[0] = f2bf(a[0]); r[1] = f2bf(a[1]); r[2] = f2bf(a[2]); r[3] = f2bf(a[3]);
  r[4] = f2bf(b[0]); r[5] = f2bf(b[1]); r[6] = f2bf(b[2]); r[7] = f2bf(b[3]);
  *((short8*)Wob + i) = *(const short8*)r;
}

// Build Wqkv_t [N=3072][K=1024] bf16 where row n = (sect,h,dd):
//   Wt[n][k] = Wsect[h][k][dd]   (transpose via LDS tile, coalesced both sides)
__global__ void k_cvt_wqkv(const float* __restrict__ Wq, const float* __restrict__ Wk,
                           const float* __restrict__ Wv, uint16_t* __restrict__ Wt) {
  __shared__ float tile[64][65];
  const int bx = blockIdx.x;
  const int sect = bx >> 8, h = (bx >> 4) & 15, kc = bx & 15;
  const float* W = sect == 0 ? Wq : (sect == 1 ? Wk : Wv);
  const float scal = sect == 0 ? QSCALE : 1.0f;
  const int t = threadIdx.x;
  const int r = t >> 2, cbase = (t & 3) * 16;
  const float* src = W + ((size_t)(h * 1024 + kc * 64 + r)) * 64 + cbase;
#pragma unroll
  for (int j = 0; j < 4; ++j) {
    float4v v = *(const float4v*)(src + j * 4);
    tile[r][cbase + j * 4 + 0] = v[0];
    tile[r][cbase + j * 4 + 1] = v[1];
    tile[r][cbase + j * 4 + 2] = v[2];
    tile[r][cbase + j * 4 + 3] = v[3];
  }
  __syncthreads();
  const int dd = t >> 2, kp = (t & 3) * 16;
  alignas(16) uint16_t tmp[16];
#pragma unroll
  for (int j = 0; j < 16; ++j) tmp[j] = f2bf(tile[kp + j][dd] * scal);
  const int n = sect * 1024 + h * 64 + dd;
  uint16_t* dst = Wt + (size_t)n * 1024 + kc * 64 + kp;
  *(short8*)dst = *(const short8*)tmp;
  *((short8*)dst + 1) = *(const short8*)(tmp + 8);
}

// ---------------- GEMM (K=1024, 128x128 tile, BK=64, dbuf LDS) ----------------
template <int MODE>
__global__ __launch_bounds__(256, 2) void gemm_k1024(
    const uint16_t* __restrict__ A, const uint16_t* __restrict__ Bt, int tiles_n,
    const float* __restrict__ bias_q, const float* __restrict__ bias_k,
    const float* __restrict__ bias_v,
    uint16_t* __restrict__ Qws, uint16_t* __restrict__ Kws, uint16_t* __restrict__ Vtws,
    float* __restrict__ outf) {
  __shared__ uint16_t As[2][128 * 64];
  __shared__ uint16_t Bs[2][128 * 64];

  const int tid = threadIdx.x, lane = tid & 63, wv = tid >> 6;
  // XCD-chunked swizzle (T1): nwg%8==0 for both modes
  const int cpx = (MODE == 0) ? 192 : 64;
  const int bid = blockIdx.x;
  const int swz = (bid & 7) * cpx + (bid >> 3);
  const int m0 = (swz / tiles_n) * 128;
  const int n0 = (swz % tiles_n) * 128;
  const int wm = (wv >> 1) * 64, wn = (wv & 1) * 64;
  const int rin = lane >> 3;
  const int csw = ((lane & 7) ^ rin) * 16;

  const char* gA = (const char*)A;
  const char* gB = (const char*)Bt;

  f32x4 acc[4][4];
#pragma unroll
  for (int mi = 0; mi < 4; ++mi)
#pragma unroll
    for (int ni = 0; ni < 4; ++ni) acc[mi][ni] = (f32x4){0.f, 0.f, 0.f, 0.f};

  auto stage = [&](int buf, int kt) {
    const int k0b = kt * 128;
#pragma unroll
    for (int i = 0; i < 4; ++i) {
      const int rb = wv * 32 + i * 8;
      gload_lds16(gA + (size_t)(m0 + rb + rin) * 2048 + k0b + csw, &As[buf][rb * 64]);
      gload_lds16(gB + (size_t)(n0 + rb + rin) * 2048 + k0b + csw, &Bs[buf][rb * 64]);
    }
  };

  stage(0, 0);
  const int kb0 = (lane >> 4) * 16;
  for (int kt = 0; kt < 16; ++kt) {
    const int buf = kt & 1;
    // single barrier per iter: also guarantees prior iter's readers finished
    // before this iter's stage overwrites their buffer (all-arrive semantics).
    __syncthreads();
    if (kt + 1 < 16) stage(buf ^ 1, kt + 1);
#pragma unroll
    for (int kk = 0; kk < 2; ++kk) {
      short8 af[4], bfr[4];
#pragma unroll
      for (int i = 0; i < 4; ++i) {
        af[i] = lds_frag(As[buf], wm + i * 16 + (lane & 15), kk * 64 + kb0);
        bfr[i] = lds_frag(Bs[buf], wn + i * 16 + (lane & 15), kk * 64 + kb0);
      }
#pragma unroll
      for (int mi = 0; mi < 4; ++mi)
#pragma unroll
        for (int ni = 0; ni < 4; ++ni) acc[mi][ni] = mfma16(af[mi], bfr[ni], acc[mi][ni]);
    }
  }

  const int col0 = n0 + wn + (lane & 15);
  const int row0 = m0 + wm + ((lane >> 4) << 2);
  if (MODE == 1) {
#pragma unroll
    for (int ni = 0; ni < 4; ++ni) {
      const int n = col0 + ni * 16;
      const float bv = bias_q[n];  // bo
#pragma unroll
      for (int mi = 0; mi < 4; ++mi) {
        const int mrow = row0 + mi * 16;
#pragma unroll
        for (int r = 0; r < 4; ++r)
          outf[(size_t)(mrow + r) * 1024 + n] = acc[mi][ni][r] + bv;
      }
    }
  } else {
#pragma unroll
    for (int ni = 0; ni < 4; ++ni) {
      const int n = col0 + ni * 16;
      const int sect = n >> 10, h = (n >> 6) & 15, dd = n & 63;
      float bv;
      if (sect == 0) bv = bias_q[h * 64 + dd] * QSCALE;
      else if (sect == 1) bv = bias_k[h * 64 + dd];
      else bv = bias_v[h * 64 + dd];
#pragma unroll
      for (int mi = 0; mi < 4; ++mi) {
        const int mrow = row0 + mi * 16;
        const int b = mrow >> 11, s = mrow & 2047;
        const int bh = b * 16 + h;
        if (sect == 2) {
          u16x4 pk;
#pragma unroll
          for (int r = 0; r < 4; ++r) pk[r] = f2bf(acc[mi][ni][r] + bv);
          *(u16x4*)(Vtws + ((size_t)bh * 64 + dd) * 2048 + s) = pk;  // V^T [bh][d][s]
        } else {
          uint16_t* dst = (sect == 0 ? Qws : Kws) + ((size_t)bh * 2048 + s) * 64 + dd;
#pragma unroll
          for (int r = 0; r < 4; ++r) dst[(size_t)r * 64] = f2bf(acc[mi][ni][r] + bv);
        }
      }
    }
  }
}

// ---------------- flash attention (swapped-QK^T, 32x32 MFMA, in-reg softmax) ----
// grid: 512 blocks = bh(64) x qtile(8); 4 waves/block, each wave owns 64 q-rows
// (2 groups of 32). Doubled per-wave q-tile halves LDS bytes per MFMA-FLOP:
// K/V fragments read once feed both q-groups' MFMAs.
// XCD-swizzled: 8 bh per XCD -> K/V working set 8*512KB = 4MB = one L2.
__global__ __launch_bounds__(256, 2) void attn_fa(
    const uint16_t* __restrict__ Qws, const uint16_t* __restrict__ Kws,
    const uint16_t* __restrict__ Vtws, uint16_t* __restrict__ AttO) {
  __shared__ uint16_t SM[2][2][64 * 64];  // [dbuf][K/V] tiles; epilogue scratch

  const int tid = threadIdx.x, lane = tid & 63, wq = tid >> 6;
  const int bid = blockIdx.x;
  const int bh = (bid & 7) * 8 + (bid >> 6);   // XCD-aware decode
  const int q0 = ((bid >> 3) & 7) * 256;
  const int hi = lane >> 5;   // lane half
  const int qc = lane & 31;   // col index (q within group; kv/d row for A-frags)

  const uint16_t* Qb = Qws + (size_t)bh * (2048 * 64);
  const uint16_t* Kb = Kws + (size_t)bh * (2048 * 64);
  const uint16_t* Vb = Vtws + (size_t)bh * (64 * 2048);

  // staging indices: 256 threads stage a 64x64 bf16 tile in 2 shots of 16B/thread
  const int lrow = lane >> 3;                       // 0..7
  const int csw = ((lane & 7) ^ lrow) * 16;         // pre-swizzled source chunk

  // Q B-frags (col=q, k=d=16c+8hi+j), 2 groups of 32 q, in registers throughout
  short8 qf[2][4];
#pragma unroll
  for (int g = 0; g < 2; ++g)
#pragma unroll
    for (int c = 0; c < 4; ++c)
      qf[g][c] = *(const short8*)(Qb + (size_t)(q0 + wq * 64 + g * 32 + qc) * 64 +
                                  c * 16 + hi * 8);

  f32x16 oA0 = {}, oA1 = {}, oB0 = {}, oB1 = {};  // O^T acc: [group][d-half]
  float mA = 8.0f, mB = 8.0f, lA = 0.0f, lB = 0.0f;

  auto stage = [&](int buf, int kt) {
    const int kv0 = kt * 64;
#pragma unroll
    for (int i = 0; i < 2; ++i) {
      const int rb = i * 32 + wq * 8;   // wave-uniform row base
      const int rt = rb + lrow;         // this lane's source row
      gload_lds16((const char*)Kb + (size_t)(kv0 + rt) * 128 + csw,
                  (char*)&SM[buf][0][0] + rb * 128);
      gload_lds16((const char*)Vb + ((size_t)rt * 2048 + kv0) * 2 + csw,
                  (char*)&SM[buf][1][0] + rb * 128);
    }
  };

  stage(0, 0);
  for (int kt = 0; kt < 32; ++kt) {
    const int buf = kt & 1;
    __syncthreads();  // staging of buf complete; prior readers of buf^1 done
    if (kt + 1 < 32) stage(buf ^ 1, kt + 1);
    const uint16_t* Kl = &SM[buf][0][0];
    const uint16_t* Vl = &SM[buf][1][0];

    // S^T = K · Q^T for both groups; K-frags read ONCE, feed 2 groups
    f32x16 pA0 = {}, pA1 = {}, pB0 = {}, pB1 = {};
    __builtin_amdgcn_s_setprio(1);
#pragma unroll
    for (int c = 0; c < 4; ++c) {
      short8 k0 = lds_frag(Kl, qc, c * 32 + hi * 16);
      short8 k1 = lds_frag(Kl, 32 + qc, c * 32 + hi * 16);
      pA0 = mfma32(k0, qf[0][c], pA0);
      pA1 = mfma32(k1, qf[0][c], pA1);
      pB0 = mfma32(k0, qf[1][c], pB0);
      pB1 = mfma32(k1, qf[1][c], pB1);
    }
    __builtin_amdgcn_s_setprio(0);

    // ---- in-register online softmax (per lane: one q per group, 32 kv) ----
    float mxA = tree_max(pA0, pA1);
    float mxB = tree_max(pB0, pB1);
    mxA = fmaxf(mxA, __shfl_xor(mxA, 32, 64));  // full row: lanes q and q+32
    mxB = fmaxf(mxB, __shfl_xor(mxB, 32, 64));
    if (__any(fmaxf(mxA - mA, mxB - mB) > 8.0f)) {  // defer-max (T13)
      const float nmA = fmaxf(mA, mxA), nmB = fmaxf(mB, mxB);
      const float alA = __builtin_amdgcn_exp2f(mA - nmA);
      const float alB = __builtin_amdgcn_exp2f(mB - nmB);
      lA *= alA; lB *= alB;
#pragma unroll
      for (int r = 0; r < 16; ++r) {
        oA0[r] *= alA; oA1[r] *= alA;
        oB0[r] *= alB; oB1[r] *= alB;
      }
      mA = nmA; mB = nmB;
    }
    short8 paA[4], paB[4];
    {
#pragma unroll
      for (int r = 0; r < 16; ++r) pA0[r] = __builtin_amdgcn_exp2f(pA0[r] - mA);
#pragma unroll
      for (int r = 0; r < 16; ++r) pA1[r] = __builtin_amdgcn_exp2f(pA1[r] - mA);
      float s[16];
#pragma unroll
      for (int r = 0; r < 16; ++r) s[r] = pA0[r] + pA1[r];
#pragma unroll
      for (int r = 0; r < 8; ++r) s[r] += s[r + 8];
#pragma unroll
      for (int r = 0; r < 4; ++r) s[r] += s[r + 4];
      float sum = (s[0] + s[1]) + (s[2] + s[3]);
      sum += __shfl_xor(sum, 32, 64);
      lA += sum;
      mk_pa(pA0, pA1, paA);
    }
    {
#pragma unroll
      for (int r = 0; r < 16; ++r) pB0[r] = __builtin_amdgcn_exp2f(pB0[r] - mB);
#pragma unroll
      for (int r = 0; r < 16; ++r) pB1[r] = __builtin_amdgcn_exp2f(pB1[r] - mB);
      float s[16];
#pragma unroll
      for (int r = 0; r < 16; ++r) s[r] = pB0[r] + pB1[r];
#pragma unroll
      for (int r = 0; r < 8; ++r) s[r] += s[r + 8];
#pragma unroll
      for (int r = 0; r < 4; ++r) s[r] += s[r + 4];
      float sum = (s[0] + s[1]) + (s[2] + s[3]);
      sum += __shfl_xor(sum, 32, 64);
      lB += sum;
      mk_pa(pB0, pB1, paB);
    }

    // ---- O^T += V^T · P^T ; V-frags read ONCE, feed 2 groups ----
    __builtin_amdgcn_s_setprio(1);
#pragma unroll
    for (int ks = 0; ks < 4; ++ks) {
      short8 v0 = lds_frag(Vl, qc, ks * 32 + hi * 16);
      short8 v1 = lds_frag(Vl, 32 + qc, ks * 32 + hi * 16);
      oA0 = mfma32(v0, paA[ks], oA0);
      oA1 = mfma32(v1, paA[ks], oA1);
      oB0 = mfma32(v0, paB[ks], oB0);
      oB1 = mfma32(v1, paB[ks], oB1);
    }
    __builtin_amdgcn_s_setprio(0);
    // no second barrier: next iter's top barrier provides the WAR protection
  }
  __syncthreads();  // protect epilogue LDS reuse against other waves' last reads

  // ---- epilogue: normalize, transpose via LDS (8KB scratch per wave) ----
  const float invA = 1.0f / lA, invB = 1.0f / lB;
#pragma unroll
  for (int r = 0; r < 16; ++r) {
    oA0[r] *= invA; oA1[r] *= invA;
    oB0[r] *= invB; oB1[r] *= invB;
  }

  char* ep = (char*)&SM[0][0][0] + wq * 8192;  // 8KB region per wave (64 rows)
#pragma unroll
  for (int g = 0; g < 2; ++g)
#pragma unroll
    for (int no = 0; no < 2; ++no)
#pragma unroll
      for (int rg = 0; rg < 4; ++rg) {
        const f32x16& oo = g ? (no ? oB1 : oB0) : (no ? oA1 : oA0);
        const int row = g * 32 + qc;
        const int d0 = no * 32 + rg * 8 + hi * 4;  // 4 consecutive d per group
        u16x4 pk;
#pragma unroll
        for (int j = 0; j < 4; ++j) pk[j] = f2bf(oo[rg * 4 + j]);
        *(u16x4*)(ep + row * 128 + ((d0 * 2) ^ ((row & 7) << 4))) = pk;
      }
  // own-region read-back (no barrier: each wave reads only its own writes)
  const int b = bh >> 4, h = bh & 15;
#pragma unroll
  for (int it = 0; it < 8; ++it) {
    const int pos = it * 64 + lane;
    const int qq = pos >> 3, c = pos & 7;
    short8 vv = *(const short8*)(ep + qq * 128 + ((c * 16) ^ ((qq & 7) << 4)));
    *(short8*)(AttO + ((size_t)b * 2048 + q0 + wq * 64 + qq) * 1024 + h * 64 + c * 8) = vv;
  }
}

// ---------------- launcher ----------------

extern "C" void kernel_launch(void* const* d_in, const int* in_sizes, int n_in,
                              void* d_out, int out_size, void* d_ws, size_t ws_size,
                              hipStream_t stream) {
  (void)in_sizes; (void)n_in; (void)out_size; (void)ws_size;
  const float* x  = (const float*)d_in[0];
  const float* Wq = (const float*)d_in[1];
  const float* bq = (const float*)d_in[2];
  const float* Wk = (const float*)d_in[3];
  const float* bk = (const float*)d_in[4];
  const float* Wv = (const float*)d_in[5];
  const float* bv = (const float*)d_in[6];
  const float* Wo = (const float*)d_in[7];
  const float* bo = (const float*)d_in[8];
  float* out = (float*)d_out;

  char* ws = (char*)d_ws;
  uint16_t* Xb   = (uint16_t*)(ws);                 // [8192][1024] bf16
  uint16_t* AttO = (uint16_t*)(ws);                 // alias (Xb dead after GEMM1)
  uint16_t* Wqkv = (uint16_t*)(ws + 16777216);      // [3072][1024] bf16
  uint16_t* Wob  = (uint16_t*)(ws + 23068672);      // [1024][1024] bf16
  uint16_t* Qws  = (uint16_t*)(ws + 25165824);      // [64][2048][64] bf16
  uint16_t* Kws  = (uint16_t*)(ws + 41943040);      // [64][2048][64] bf16
  uint16_t* Vt   = (uint16_t*)(ws + 58720256);      // [64][64][2048] bf16

  k_cvt_x<<<4096, 256, 0, stream>>>(x, Xb);
  k_cvt_wqkv<<<768, 256, 0, stream>>>(Wq, Wk, Wv, Wqkv);
  k_cvt_wo<<<512, 256, 0, stream>>>(Wo, Wob);
  gemm_k1024<0><<<64 * 24, 256, 0, stream>>>(Xb, Wqkv, 24, bq, bk, bv, Qws, Kws, Vt, nullptr);
  attn_fa<<<512, 256, 0, stream>>>(Qws, Kws, Vt, AttO);
  gemm_k1024<1><<<64 * 8, 256, 0, stream>>>(AttO, Wob, 8, bo, nullptr, nullptr,
                                            nullptr, nullptr, nullptr, out);
}